// Round 1
// baseline (41133.969 us; speedup 1.0000x reference)
//
#include <hip/hip_runtime.h>
#include <hip/hip_bf16.h>
#include <math.h>

// Problem constants
#define B_    32
#define S_    2048
#define E_    300
#define H_    256
#define STEPS_ 24
#define BS_   (B_ * S_)      // 65536
#define H3_   (3 * H_)       // 768

#define MT 16                // M-tile rows per block

__device__ __forceinline__ float sigm(float x) {
    return 1.0f / (1.0f + __expf(-x));
}

// ---------------------------------------------------------------------------
// Projection: x_iou[b,s,0:768] = input @ W_iou + b_iou ; x_f = input @ W_f + b_f
// Stored as bf16 in ws. One block = 16 rows, 256 threads; thread owns cols
// {tid, tid+256, tid+512} of x_iou and col tid of x_f.
// ---------------------------------------------------------------------------
__global__ __launch_bounds__(256) void proj_kernel(
    const float* __restrict__ input,
    const float* __restrict__ W_iou, const float* __restrict__ b_iou,
    const float* __restrict__ W_f,   const float* __restrict__ b_f,
    __hip_bfloat16* __restrict__ x_iou, __hip_bfloat16* __restrict__ x_f)
{
    const int tid = threadIdx.x;
    const int row0 = blockIdx.x * MT;

    __shared__ float shA[MT * 304];          // 300 cols padded to 304

    // Stage A tile: 16 rows x 300 floats = 75 float4 per row (exact)
    const float4* src = (const float4*)(input + (size_t)row0 * E_);
    float4* dst = (float4*)shA;
    for (int i = tid; i < MT * 76; i += 256) {
        int rr = i / 76, c4 = i - rr * 76;
        float4 v = make_float4(0.f, 0.f, 0.f, 0.f);
        if (c4 < 75) v = src[rr * 75 + c4];
        dst[rr * 76 + c4] = v;
    }
    __syncthreads();

    float acc[MT][4];
#pragma unroll
    for (int r = 0; r < MT; ++r)
#pragma unroll
        for (int j = 0; j < 4; ++j) acc[r][j] = 0.f;

    for (int k4 = 0; k4 < 75; ++k4) {
        const int k = k4 * 4;
        float w[4][4];
#pragma unroll
        for (int kk = 0; kk < 4; ++kk) {
            const int kr = k + kk;
            const float* Wp = W_iou + (size_t)kr * H3_ + tid;
            w[kk][0] = Wp[0];
            w[kk][1] = Wp[256];
            w[kk][2] = Wp[512];
            w[kk][3] = W_f[(size_t)kr * H_ + tid];
        }
#pragma unroll
        for (int rr = 0; rr < MT; ++rr) {
            const float4 a = *(const float4*)&shA[rr * 304 + k];
            const float av[4] = {a.x, a.y, a.z, a.w};
#pragma unroll
            for (int kk = 0; kk < 4; ++kk) {
#pragma unroll
                for (int j = 0; j < 4; ++j)
                    acc[rr][j] += av[kk] * w[kk][j];
            }
        }
    }

    const float bi0 = b_iou[tid], bi1 = b_iou[256 + tid], bi2 = b_iou[512 + tid];
    const float bf = b_f[tid];
#pragma unroll
    for (int rr = 0; rr < MT; ++rr) {
        const size_t row = (size_t)(row0 + rr);
        x_iou[row * H3_ + tid]       = __float2bfloat16(acc[rr][0] + bi0);
        x_iou[row * H3_ + 256 + tid] = __float2bfloat16(acc[rr][1] + bi1);
        x_iou[row * H3_ + 512 + tid] = __float2bfloat16(acc[rr][2] + bi2);
        x_f[row * H_ + tid]          = __float2bfloat16(acc[rr][3] + bf);
    }
}

// ---------------------------------------------------------------------------
// Winner computation: winner[t][b][d] = max s with tree_ids[b][t][s] == d
// (numpy last-occurrence-wins semantics for duplicate scatter indices)
// ---------------------------------------------------------------------------
__global__ void winner_kernel(const int* __restrict__ tree_ids,
                              int* __restrict__ winner)
{
    const int idx = blockIdx.x * 256 + threadIdx.x;   // over B*STEPS*S
    if (idx >= B_ * STEPS_ * S_) return;
    const int b = idx / (STEPS_ * S_);
    const int rem = idx - b * STEPS_ * S_;
    const int t = rem / S_;
    const int s = rem - t * S_;
    const int d = tree_ids[idx];
    if ((unsigned)d < (unsigned)S_)
        atomicMax(&winner[(size_t)t * BS_ + b * S_ + d], s);
}

// ---------------------------------------------------------------------------
// Copy-through: destinations with no winner keep old value; slot 0 zeroed.
// One thread = one float4 of h and one of c.
// ---------------------------------------------------------------------------
__global__ __launch_bounds__(256) void copy_kernel(
    const float4* __restrict__ h_cur, const float4* __restrict__ c_cur,
    float4* __restrict__ h_next, float4* __restrict__ c_next,
    const int* __restrict__ winner_t)
{
    const int idx = blockIdx.x * 256 + threadIdx.x;   // BS*H/4 = 4.19M
    const int row = idx >> 6;                         // H/4 = 64 float4 per row
    const int d = row & (S_ - 1);
    if (d == 0) {
        const float4 z = make_float4(0.f, 0.f, 0.f, 0.f);
        h_next[idx] = z;
        c_next[idx] = z;
    } else if (winner_t[row] < 0) {
        h_next[idx] = h_cur[idx];
        c_next[idx] = c_cur[idx];
    }
}

// ---------------------------------------------------------------------------
// Fused step: gather h_l/h_r -> GEMM [16,256]x[256,1280] -> activations ->
// gather c_l/c_r -> winner-conditional scatter to h_next/c_next.
// Thread tid owns h-column tid; acc[r][j]: j = {i, o, u, f_l, f_r} gate chunk.
// ---------------------------------------------------------------------------
__global__ __launch_bounds__(256) void step_kernel(
    const float* __restrict__ h_cur, const float* __restrict__ c_cur,
    float* __restrict__ h_next, float* __restrict__ c_next,
    const int* __restrict__ tree_ids,    // idd
    const int* __restrict__ tree_ids_l,  // idl
    const int* __restrict__ tree_ids_r,  // idr
    const int* __restrict__ winner_t,    // [B][S]
    const __hip_bfloat16* __restrict__ x_iou,
    const __hip_bfloat16* __restrict__ x_f,
    const float* __restrict__ U_iou_l, const float* __restrict__ U_iou_r,
    const float* __restrict__ U_f_ll,  const float* __restrict__ U_f_lr,
    const float* __restrict__ U_f_rl,  const float* __restrict__ U_f_rr,
    int t)
{
    const int b = blockIdx.x >> 7;            // S/MT = 128 tiles per batch
    const int tile = blockIdx.x & 127;
    const int s0 = tile * MT;
    const int tid = threadIdx.x;

    __shared__ float shl[MT][H_];
    __shared__ float shr[MT][H_];

    const int* idd_b = tree_ids   + ((size_t)b * STEPS_ + t) * S_;
    const int* idl_b = tree_ids_l + ((size_t)b * STEPS_ + t) * S_;
    const int* idr_b = tree_ids_r + ((size_t)b * STEPS_ + t) * S_;

    // Stage gathered h_l / h_r tiles: 16 threads per row, 4 float4 each
    {
        const int r = tid >> 4, l16 = tid & 15;
        const int li = idl_b[s0 + r];
        const int ri = idr_b[s0 + r];
        const float4* hl_src = (const float4*)(h_cur + ((size_t)b * S_ + li) * H_);
        const float4* hr_src = (const float4*)(h_cur + ((size_t)b * S_ + ri) * H_);
        float4* shl4 = (float4*)&shl[r][0];
        float4* shr4 = (float4*)&shr[r][0];
#pragma unroll
        for (int j = 0; j < 4; ++j) {
            shl4[l16 + 16 * j] = hl_src[l16 + 16 * j];
            shr4[l16 + 16 * j] = hr_src[l16 + 16 * j];
        }
    }
    __syncthreads();

    float acc[MT][5];
#pragma unroll
    for (int r = 0; r < MT; ++r)
#pragma unroll
        for (int j = 0; j < 5; ++j) acc[r][j] = 0.f;

    for (int k4 = 0; k4 < H_ / 4; ++k4) {
        const int k = k4 * 4;
        float ul[4][5], ur[4][5];
#pragma unroll
        for (int kk = 0; kk < 4; ++kk) {
            const int kr = k + kk;
            const float* Ul3 = U_iou_l + (size_t)kr * H3_ + tid;
            ul[kk][0] = Ul3[0];
            ul[kk][1] = Ul3[256];
            ul[kk][2] = Ul3[512];
            ul[kk][3] = U_f_ll[(size_t)kr * H_ + tid];
            ul[kk][4] = U_f_rl[(size_t)kr * H_ + tid];
            const float* Ur3 = U_iou_r + (size_t)kr * H3_ + tid;
            ur[kk][0] = Ur3[0];
            ur[kk][1] = Ur3[256];
            ur[kk][2] = Ur3[512];
            ur[kk][3] = U_f_lr[(size_t)kr * H_ + tid];
            ur[kk][4] = U_f_rr[(size_t)kr * H_ + tid];
        }
#pragma unroll
        for (int rr = 0; rr < MT; ++rr) {
            const float4 al = *(const float4*)&shl[rr][k];
            const float4 ar = *(const float4*)&shr[rr][k];
            const float a0[4] = {al.x, al.y, al.z, al.w};
            const float a1[4] = {ar.x, ar.y, ar.z, ar.w};
#pragma unroll
            for (int kk = 0; kk < 4; ++kk) {
#pragma unroll
                for (int j = 0; j < 5; ++j)
                    acc[rr][j] += a0[kk] * ul[kk][j] + a1[kk] * ur[kk][j];
            }
        }
    }

    // Epilogue: winner-conditional scatter (branch is uniform per row)
#pragma unroll 1
    for (int rr = 0; rr < MT; ++rr) {
        const int s = s0 + rr;
        const int d = idd_b[s];
        if (d == 0) continue;
        if (winner_t[b * S_ + d] != s) continue;

        const size_t xrow = (size_t)(b * S_ + s);
        const float xi0 = __bfloat162float(x_iou[xrow * H3_ + tid]);
        const float xi1 = __bfloat162float(x_iou[xrow * H3_ + 256 + tid]);
        const float xi2 = __bfloat162float(x_iou[xrow * H3_ + 512 + tid]);
        const float xf  = __bfloat162float(x_f[xrow * H_ + tid]);

        const float i_g = sigm(acc[rr][0] + xi0);
        const float o_g = sigm(acc[rr][1] + xi1);
        const float u_g = tanhf(acc[rr][2] + xi2);
        const float fl  = sigm(acc[rr][3] + xf);
        const float fr  = sigm(acc[rr][4] + xf);

        const int li = idl_b[s];
        const int ri = idr_b[s];
        const float cl = c_cur[((size_t)b * S_ + li) * H_ + tid];
        const float cr = c_cur[((size_t)b * S_ + ri) * H_ + tid];

        const float c_new = i_g * u_g + fl * cl + fr * cr;
        const float h_new = o_g * tanhf(c_new);

        h_next[((size_t)b * S_ + d) * H_ + tid] = h_new;
        c_next[((size_t)b * S_ + d) * H_ + tid] = c_new;
    }
}

// ---------------------------------------------------------------------------
// Root extraction: roots[b] = max_s tree_ids[b, STEPS-1, s]; h_root = h[b, root]
// ---------------------------------------------------------------------------
__global__ __launch_bounds__(256) void root_kernel(
    const int* __restrict__ tree_ids,
    const float* __restrict__ h, float* __restrict__ h_root)
{
    const int b = blockIdx.x;
    const int tid = threadIdx.x;
    const int* ids = tree_ids + ((size_t)b * STEPS_ + (STEPS_ - 1)) * S_;
    __shared__ int red[256];
    int m = 0;
    for (int s = tid; s < S_; s += 256) m = max(m, ids[s]);
    red[tid] = m;
    __syncthreads();
    for (int off = 128; off > 0; off >>= 1) {
        if (tid < off) red[tid] = max(red[tid], red[tid + off]);
        __syncthreads();
    }
    const int root = red[0];
    h_root[(size_t)b * H_ + tid] = h[((size_t)b * S_ + root) * H_ + tid];
}

// ---------------------------------------------------------------------------
extern "C" void kernel_launch(void* const* d_in, const int* in_sizes, int n_in,
                              void* d_out, int out_size, void* d_ws, size_t ws_size,
                              hipStream_t stream)
{
    const float* input_ids  = (const float*)d_in[0];
    const int*   tree_ids   = (const int*)d_in[1];
    const int*   tree_ids_r = (const int*)d_in[2];
    const int*   tree_ids_l = (const int*)d_in[3];
    const float* W_iou   = (const float*)d_in[4];
    const float* b_iou   = (const float*)d_in[5];
    const float* U_iou_l = (const float*)d_in[6];
    const float* U_iou_r = (const float*)d_in[7];
    const float* W_f     = (const float*)d_in[8];
    const float* b_f     = (const float*)d_in[9];
    const float* U_f_ll  = (const float*)d_in[10];
    const float* U_f_lr  = (const float*)d_in[11];
    const float* U_f_rl  = (const float*)d_in[12];
    const float* U_f_rr  = (const float*)d_in[13];

    float* out = (float*)d_out;
    float* out_h = out;
    float* out_c = out + (size_t)BS_ * H_;
    float* out_root = out + (size_t)2 * BS_ * H_;

    // ws layout (bytes):
    //   x_iou bf16 [BS][768] : 0          .. 100663296
    //   x_f   bf16 [BS][256] : 100663296  .. 134217728
    //   ws_h  fp32 [BS][256] : 134217728  .. 201326592
    //   ws_c  fp32 [BS][256] : 201326592  .. 268435456
    //   winner int [24][B][S]: 268435456  .. 274726912
    char* ws = (char*)d_ws;
    __hip_bfloat16* x_iou = (__hip_bfloat16*)(ws);
    __hip_bfloat16* x_f   = (__hip_bfloat16*)(ws + 100663296ull);
    float* ws_h = (float*)(ws + 134217728ull);
    float* ws_c = (float*)(ws + 201326592ull);
    int* winner = (int*)(ws + 268435456ull);

    // Zero-init h0/c0 (they live in d_out; 24 even steps ping-pong back here)
    hipMemsetAsync(d_out, 0, (size_t)2 * BS_ * H_ * sizeof(float), stream);
    // winner = -1
    hipMemsetAsync(winner, 0xFF, (size_t)STEPS_ * BS_ * sizeof(int), stream);

    proj_kernel<<<BS_ / MT, 256, 0, stream>>>(input_ids, W_iou, b_iou, W_f, b_f,
                                              x_iou, x_f);
    winner_kernel<<<(B_ * STEPS_ * S_) / 256, 256, 0, stream>>>(tree_ids, winner);

    for (int t = 0; t < STEPS_; ++t) {
        const float* ch = (t & 1) ? ws_h : out_h;
        const float* cc = (t & 1) ? ws_c : out_c;
        float* nh = (t & 1) ? out_h : ws_h;
        float* nc = (t & 1) ? out_c : ws_c;
        const int* wt = winner + (size_t)t * BS_;

        copy_kernel<<<(BS_ * H_ / 4) / 256, 256, 0, stream>>>(
            (const float4*)ch, (const float4*)cc, (float4*)nh, (float4*)nc, wt);

        step_kernel<<<B_ * (S_ / MT), 256, 0, stream>>>(
            ch, cc, nh, nc, tree_ids, tree_ids_l, tree_ids_r, wt,
            x_iou, x_f, U_iou_l, U_iou_r, U_f_ll, U_f_lr, U_f_rl, U_f_rr, t);
    }

    root_kernel<<<B_, 256, 0, stream>>>(tree_ids, out_h, out_root);
}

// Round 2
// 7935.828 us; speedup vs baseline: 5.1833x; 5.1833x over previous
//
#include <hip/hip_runtime.h>
#include <hip/hip_bf16.h>
#include <math.h>

// Problem constants
#define B_     32
#define S_     2048
#define E_     300
#define H_     256
#define STEPS_ 24
#define BS_    (B_ * S_)      // 65536
#define NPACK  1280           // 5 gates * 256
#define KTOT   512            // h_l(256) ++ h_r(256)
#define KSL    16             // 512/32 k-slabs
#define KP     320            // proj K padded (300 -> 320)
#define KSLP   10             // 320/32

typedef __bf16 bf16x8 __attribute__((ext_vector_type(8)));
typedef float  f32x4  __attribute__((ext_vector_type(4)));

__device__ __forceinline__ float sigm(float x) {
    return 1.0f / (1.0f + __expf(-x));
}
__device__ __forceinline__ float fast_tanh(float x) {
    return 2.0f * sigm(2.0f * x) - 1.0f;
}

// ---------------------------------------------------------------------------
// Pack step-GEMM B: Bp[ks][p][kin], p = w*80 + g*16 + c_lo, col c = w*16+c_lo.
// k<256 -> U_*_l[k], k>=256 -> U_*_r[k-256]. Gates: 0=i,1=o,2=u,3=f_l,4=f_r.
// ---------------------------------------------------------------------------
__global__ __launch_bounds__(256) void pack_B_kernel(
    const float* __restrict__ U_iou_l, const float* __restrict__ U_iou_r,
    const float* __restrict__ U_f_ll,  const float* __restrict__ U_f_lr,
    const float* __restrict__ U_f_rl,  const float* __restrict__ U_f_rr,
    __hip_bfloat16* __restrict__ Bp)
{
    const int idx = blockIdx.x * 256 + threadIdx.x;      // 16*1280*32 = 655360
    if (idx >= KSL * NPACK * 32) return;
    const int ks = idx / (NPACK * 32);
    const int rem = idx - ks * (NPACK * 32);
    const int p = rem >> 5;
    const int kin = rem & 31;
    const int k = ks * 32 + kin;
    const int w = p / 80;
    const int rg = p - w * 80;
    const int g = rg >> 4;
    const int c = w * 16 + (rg & 15);
    float v;
    if (g < 3) {
        const int col = g * 256 + c;
        v = (k < 256) ? U_iou_l[k * 768 + col] : U_iou_r[(k - 256) * 768 + col];
    } else if (g == 3) {
        v = (k < 256) ? U_f_ll[k * 256 + c] : U_f_lr[(k - 256) * 256 + c];
    } else {
        v = (k < 256) ? U_f_rl[k * 256 + c] : U_f_rr[(k - 256) * 256 + c];
    }
    Bp[idx] = __float2bfloat16(v);
}

// ---------------------------------------------------------------------------
// Pack projection weights: Wp[ks][p][kin]; p<768 -> W_iou col p, else W_f col
// p-768. k>=300 zero-padded.
// ---------------------------------------------------------------------------
__global__ __launch_bounds__(256) void pack_W_kernel(
    const float* __restrict__ W_iou, const float* __restrict__ W_f,
    __hip_bfloat16* __restrict__ Wp)
{
    const int idx = blockIdx.x * 256 + threadIdx.x;      // 10*1024*32 = 327680
    if (idx >= KSLP * 1024 * 32) return;
    const int ks = idx / (1024 * 32);
    const int rem = idx - ks * (1024 * 32);
    const int p = rem >> 5;
    const int kin = rem & 31;
    const int k = ks * 32 + kin;
    float v = 0.f;
    if (k < E_) v = (p < 768) ? W_iou[k * 768 + p] : W_f[k * 256 + (p - 768)];
    Wp[idx] = __float2bfloat16(v);
}

// ---------------------------------------------------------------------------
// Winner: winner[t][b][d] = max s with tree_ids[b][t][s]==d (last-wins scatter)
// ---------------------------------------------------------------------------
__global__ __launch_bounds__(256) void winner_kernel(
    const int* __restrict__ tree_ids, int* __restrict__ winner)
{
    const int idx = blockIdx.x * 256 + threadIdx.x;
    if (idx >= B_ * STEPS_ * S_) return;
    const int b = idx / (STEPS_ * S_);
    const int rem = idx - b * (STEPS_ * S_);
    const int t = rem / S_;
    const int s = rem - t * S_;
    const int d = tree_ids[idx];
    if ((unsigned)d < (unsigned)S_)
        atomicMax(&winner[(size_t)t * BS_ + b * S_ + d], s);
}

// ---------------------------------------------------------------------------
// Projection GEMM (MFMA): x_all[BS][1024] bf16 = [input|pad] @ Wp + bias.
// Block: 256 thr, M=16, N=1024 (wave owns 16 n-tiles), K=320.
// ---------------------------------------------------------------------------
__global__ __launch_bounds__(256) void proj_kernel(
    const float* __restrict__ input, const __hip_bfloat16* __restrict__ Wp,
    const float* __restrict__ b_iou, const float* __restrict__ b_f,
    __hip_bfloat16* __restrict__ x_all)
{
    __shared__ __hip_bfloat16 Ash[16][328];              // +8 pad
    const int tid = threadIdx.x;
    const int row0 = blockIdx.x * 16;

    // Stage A: fp32 -> bf16, 16 rows x 320 (zeros past 300)
    for (int it = 0; it < 5; ++it) {
        const int idx = tid + it * 256;                  // 0..1279 = 16 rows * 80 chunks
        const int r = idx / 80;
        const int c4 = idx - r * 80;
        float4 v = make_float4(0.f, 0.f, 0.f, 0.f);
        if (c4 < 75) v = *(const float4*)(input + (size_t)(row0 + r) * E_ + c4 * 4);
        union { __hip_bfloat16 h[4]; uint2 u; } tconv;
        tconv.h[0] = __float2bfloat16(v.x);
        tconv.h[1] = __float2bfloat16(v.y);
        tconv.h[2] = __float2bfloat16(v.z);
        tconv.h[3] = __float2bfloat16(v.w);
        *(uint2*)&Ash[r][c4 * 4] = tconv.u;
    }
    __syncthreads();

    const int lane = tid & 63;
    const int wave = tid >> 6;
    const int m16 = lane & 15;
    const int q = lane >> 4;

    f32x4 acc[16];
    const f32x4 z4 = {0.f, 0.f, 0.f, 0.f};
#pragma unroll
    for (int nt = 0; nt < 16; ++nt) acc[nt] = z4;

    const __hip_bfloat16* wp = Wp + ((size_t)(wave * 256 + m16)) * 32 + q * 8;
    for (int ks = 0; ks < KSLP; ++ks) {
        const bf16x8 a = *reinterpret_cast<const bf16x8*>(&Ash[m16][ks * 32 + q * 8]);
        const __hip_bfloat16* wk = wp + (size_t)ks * 32768;
#pragma unroll
        for (int nt = 0; nt < 16; ++nt) {
            const bf16x8 bb = *reinterpret_cast<const bf16x8*>(wk + nt * 512);
            acc[nt] = __builtin_amdgcn_mfma_f32_16x16x32_bf16(a, bb, acc[nt], 0, 0, 0);
        }
    }

#pragma unroll
    for (int j = 0; j < 4; ++j) {
        const int row = row0 + q * 4 + j;
        const size_t xrow = (size_t)row * 1024;
#pragma unroll
        for (int nt = 0; nt < 16; ++nt) {
            const int col = wave * 256 + nt * 16 + m16;
            const float bias = (col < 768) ? b_iou[col] : b_f[col - 768];
            x_all[xrow + col] = __float2bfloat16(acc[nt][j] + bias);
        }
    }
}

// ---------------------------------------------------------------------------
// Copy-through + null-slot zero. idx over BS*64 float4-chunks of c (16B) and
// matching 8B chunks of h (bf16).
// ---------------------------------------------------------------------------
__global__ __launch_bounds__(256) void copy_kernel(
    const float4* __restrict__ c_cur4, float4* __restrict__ c_next4,
    const uint2* __restrict__ h_cur2, uint2* __restrict__ h_next2,
    const int* __restrict__ winner_t)
{
    const int idx = blockIdx.x * 256 + threadIdx.x;      // BS*64
    const int row = idx >> 6;
    const int d = row & (S_ - 1);
    if (d == 0) {
        c_next4[idx] = make_float4(0.f, 0.f, 0.f, 0.f);
        h_next2[idx] = make_uint2(0u, 0u);
    } else if (winner_t[row] < 0) {
        c_next4[idx] = c_cur4[idx];
        h_next2[idx] = h_cur2[idx];
    }
}

// ---------------------------------------------------------------------------
// Fused MFMA step: gather h_l/h_r (bf16) -> [32,512]x[512,1280] -> gates ->
// gather c, winner-conditional scatter.  Block: 256 thr (4 waves), M=32
// (2 sub-M of 16 sharing B-frags), each wave owns 4 w-groups x 5 gates.
// ---------------------------------------------------------------------------
__global__ __launch_bounds__(256, 2) void step_kernel(
    const __hip_bfloat16* __restrict__ h_cur, const float* __restrict__ c_cur,
    __hip_bfloat16* __restrict__ h_next, float* __restrict__ c_next,
    const int* __restrict__ tree_ids, const int* __restrict__ tree_ids_l,
    const int* __restrict__ tree_ids_r, const int* __restrict__ winner_t,
    const __hip_bfloat16* __restrict__ x_all,
    const __hip_bfloat16* __restrict__ Bp, int t)
{
    const int b = blockIdx.x >> 6;            // 64 tiles of 32 rows per batch
    const int tile = blockIdx.x & 63;
    const int s0 = tile * 32;
    const int tid = threadIdx.x;

    __shared__ __hip_bfloat16 Ash[32][520];   // 32 rows x (512 + 8 pad)
    __shared__ int sIdl[32], sIdr[32], sIdd[32];

    const int* idd_b = tree_ids   + ((size_t)b * STEPS_ + t) * S_;
    const int* idl_b = tree_ids_l + ((size_t)b * STEPS_ + t) * S_;
    const int* idr_b = tree_ids_r + ((size_t)b * STEPS_ + t) * S_;

    if (tid < 32)       sIdl[tid]      = idl_b[s0 + tid];
    else if (tid < 64)  sIdr[tid - 32] = idr_b[s0 + tid - 32];
    else if (tid < 96)  sIdd[tid - 64] = idd_b[s0 + tid - 64];
    __syncthreads();

    // Stage gathered A tile: row r = [h_l(idl) | h_r(idr)], 16B chunks
#pragma unroll
    for (int it = 0; it < 8; ++it) {
        const int idx = tid + it * 256;       // 0..2047
        const int r = idx >> 6;               // 64 chunks per row
        const int ch = idx & 63;
        const int half = ch >> 5;
        const int c16 = ch & 31;
        const int src = half ? sIdr[r] : sIdl[r];
        const uint4 v = *(const uint4*)(h_cur + ((size_t)(b * S_) + src) * H_ + c16 * 8);
        *(uint4*)&Ash[r][half * 256 + c16 * 8] = v;
    }
    __syncthreads();

    const int lane = tid & 63;
    const int wave = tid >> 6;
    const int m16 = lane & 15;
    const int q = lane >> 4;

    f32x4 acc[2][4][5];
    const f32x4 z4 = {0.f, 0.f, 0.f, 0.f};
#pragma unroll
    for (int sm = 0; sm < 2; ++sm)
#pragma unroll
        for (int wg = 0; wg < 4; ++wg)
#pragma unroll
            for (int g = 0; g < 5; ++g) acc[sm][wg][g] = z4;

    const __hip_bfloat16* bp_base = Bp + ((size_t)(wave * 320 + m16)) * 32 + q * 8;

    for (int ks = 0; ks < KSL; ++ks) {
        const bf16x8 a0 = *reinterpret_cast<const bf16x8*>(&Ash[m16][ks * 32 + q * 8]);
        const bf16x8 a1 = *reinterpret_cast<const bf16x8*>(&Ash[16 + m16][ks * 32 + q * 8]);
        const __hip_bfloat16* bk = bp_base + (size_t)ks * (NPACK * 32);
#pragma unroll
        for (int wg = 0; wg < 4; ++wg) {
            bf16x8 bfrag[5];
#pragma unroll
            for (int g = 0; g < 5; ++g)
                bfrag[g] = *reinterpret_cast<const bf16x8*>(bk + (wg * 80 + g * 16) * 32);
#pragma unroll
            for (int g = 0; g < 5; ++g) {
                acc[0][wg][g] = __builtin_amdgcn_mfma_f32_16x16x32_bf16(a0, bfrag[g], acc[0][wg][g], 0, 0, 0);
                acc[1][wg][g] = __builtin_amdgcn_mfma_f32_16x16x32_bf16(a1, bfrag[g], acc[1][wg][g], 0, 0, 0);
            }
        }
    }

    // Epilogue: C layout col=lane&15, row=q*4+j (per 16x16 sub-tile)
#pragma unroll
    for (int sm = 0; sm < 2; ++sm) {
#pragma unroll
        for (int j = 0; j < 4; ++j) {
            const int r = sm * 16 + q * 4 + j;    // local row
            const int s = s0 + r;
            const int d = sIdd[r];
            if (d == 0) continue;
            if (winner_t[b * S_ + d] != s) continue;
            const int li = sIdl[r], ri = sIdr[r];
            const size_t xrow = ((size_t)(b * S_ + s)) * 1024;
            const size_t crl = ((size_t)(b * S_ + li)) * H_;
            const size_t crr = ((size_t)(b * S_ + ri)) * H_;
            const size_t orow = ((size_t)(b * S_ + d)) * H_;
#pragma unroll
            for (int wg = 0; wg < 4; ++wg) {
                const int c = (wave * 4 + wg) * 16 + m16;
                const float xi = __bfloat162float(x_all[xrow + c]);
                const float xo = __bfloat162float(x_all[xrow + 256 + c]);
                const float xu = __bfloat162float(x_all[xrow + 512 + c]);
                const float xf = __bfloat162float(x_all[xrow + 768 + c]);
                const float ig = sigm(acc[sm][wg][0][j] + xi);
                const float og = sigm(acc[sm][wg][1][j] + xo);
                const float ug = fast_tanh(acc[sm][wg][2][j] + xu);
                const float fl = sigm(acc[sm][wg][3][j] + xf);
                const float fr = sigm(acc[sm][wg][4][j] + xf);
                const float cl = c_cur[crl + c];
                const float cr = c_cur[crr + c];
                const float cn = ig * ug + fl * cl + fr * cr;
                const float hn = og * fast_tanh(cn);
                c_next[orow + c] = cn;
                h_next[orow + c] = __float2bfloat16(hn);
            }
        }
    }
}

// ---------------------------------------------------------------------------
// Final h bf16 -> fp32 into d_out
// ---------------------------------------------------------------------------
__global__ __launch_bounds__(256) void convert_kernel(
    const __hip_bfloat16* __restrict__ h, float* __restrict__ out)
{
    const size_t i = ((size_t)blockIdx.x * 256 + threadIdx.x) * 8;
#pragma unroll
    for (int j = 0; j < 8; ++j) out[i + j] = __bfloat162float(h[i + j]);
}

// ---------------------------------------------------------------------------
// Root: roots[b] = max_s tree_ids[b, STEPS-1, s]; h_root = h[b, root]
// ---------------------------------------------------------------------------
__global__ __launch_bounds__(256) void root_kernel(
    const int* __restrict__ tree_ids,
    const __hip_bfloat16* __restrict__ h, float* __restrict__ h_root)
{
    const int b = blockIdx.x;
    const int tid = threadIdx.x;
    const int* ids = tree_ids + ((size_t)b * STEPS_ + (STEPS_ - 1)) * S_;
    __shared__ int red[256];
    int m = 0;
    for (int s = tid; s < S_; s += 256) m = max(m, ids[s]);
    red[tid] = m;
    __syncthreads();
    for (int off = 128; off > 0; off >>= 1) {
        if (tid < off) red[tid] = max(red[tid], red[tid + off]);
        __syncthreads();
    }
    const int root = red[0];
    h_root[(size_t)b * H_ + tid] =
        __bfloat162float(h[((size_t)(b * S_) + root) * H_ + tid]);
}

// ---------------------------------------------------------------------------
extern "C" void kernel_launch(void* const* d_in, const int* in_sizes, int n_in,
                              void* d_out, int out_size, void* d_ws, size_t ws_size,
                              hipStream_t stream)
{
    const float* input_ids  = (const float*)d_in[0];
    const int*   tree_ids   = (const int*)d_in[1];
    const int*   tree_ids_r = (const int*)d_in[2];
    const int*   tree_ids_l = (const int*)d_in[3];
    const float* W_iou   = (const float*)d_in[4];
    const float* b_iou   = (const float*)d_in[5];
    const float* U_iou_l = (const float*)d_in[6];
    const float* U_iou_r = (const float*)d_in[7];
    const float* W_f     = (const float*)d_in[8];
    const float* b_f     = (const float*)d_in[9];
    const float* U_f_ll  = (const float*)d_in[10];
    const float* U_f_lr  = (const float*)d_in[11];
    const float* U_f_rl  = (const float*)d_in[12];
    const float* U_f_rr  = (const float*)d_in[13];

    float* out = (float*)d_out;
    float* out_h = out;
    float* out_c = out + (size_t)BS_ * H_;
    float* out_root = out + (size_t)2 * BS_ * H_;

    // ws layout (bytes):
    //   x_all bf16 [BS][1024]  : 0          .. 134217728
    //   hA    bf16 [BS][256]   : 134217728  .. 167772160
    //   ws_c  fp32 [BS][256]   : 167772160  .. 234881024
    //   winner int [24][B][S]  : 234881024  .. 241172480
    //   Bp    bf16 [16][1280][32]: 241172480 .. 242483200
    //   Wp    bf16 [10][1024][32]: 242483200 .. 243138560
    char* ws = (char*)d_ws;
    __hip_bfloat16* x_all = (__hip_bfloat16*)(ws);
    __hip_bfloat16* hA    = (__hip_bfloat16*)(ws + 134217728ull);
    float*          ws_c  = (float*)(ws + 167772160ull);
    int*            winner = (int*)(ws + 234881024ull);
    __hip_bfloat16* Bp    = (__hip_bfloat16*)(ws + 241172480ull);
    __hip_bfloat16* Wp    = (__hip_bfloat16*)(ws + 242483200ull);
    // h ping-pong partner lives in the (unused during the loop) out_h region
    __hip_bfloat16* hB    = (__hip_bfloat16*)out_h;

    hipMemsetAsync(hA, 0, (size_t)BS_ * H_ * sizeof(__hip_bfloat16), stream);
    hipMemsetAsync(out_c, 0, (size_t)BS_ * H_ * sizeof(float), stream);
    hipMemsetAsync(winner, 0xFF, (size_t)STEPS_ * BS_ * sizeof(int), stream);

    pack_B_kernel<<<(KSL * NPACK * 32 + 255) / 256, 256, 0, stream>>>(
        U_iou_l, U_iou_r, U_f_ll, U_f_lr, U_f_rl, U_f_rr, Bp);
    pack_W_kernel<<<(KSLP * 1024 * 32 + 255) / 256, 256, 0, stream>>>(W_iou, W_f, Wp);
    winner_kernel<<<(B_ * STEPS_ * S_) / 256, 256, 0, stream>>>(tree_ids, winner);
    proj_kernel<<<BS_ / 16, 256, 0, stream>>>(input_ids, Wp, b_iou, b_f, x_all);

    for (int t = 0; t < STEPS_; ++t) {
        const __hip_bfloat16* hc = (t & 1) ? hB : hA;
        __hip_bfloat16*       hn = (t & 1) ? hA : hB;
        const float* cc = (t & 1) ? ws_c : out_c;
        float*       cn = (t & 1) ? out_c : ws_c;
        const int* wt = winner + (size_t)t * BS_;

        copy_kernel<<<(BS_ * (H_ / 4)) / 256, 256, 0, stream>>>(
            (const float4*)cc, (float4*)cn, (const uint2*)hc, (uint2*)hn, wt);

        step_kernel<<<B_ * (S_ / 32), 256, 0, stream>>>(
            hc, cc, hn, cn, tree_ids, tree_ids_l, tree_ids_r, wt,
            x_all, Bp, t);
    }

    // final h is in hA (t=23 odd writes hA); convert to fp32 into d_out
    convert_kernel<<<(BS_ * H_ / 8) / 256, 256, 0, stream>>>(hA, out_h);
    root_kernel<<<B_, 256, 0, stream>>>(tree_ids, hA, out_root);
}

// Round 3
// 7526.529 us; speedup vs baseline: 5.4652x; 1.0544x over previous
//
#include <hip/hip_runtime.h>
#include <hip/hip_bf16.h>
#include <math.h>

// Problem constants
#define B_     32
#define S_     2048
#define E_     300
#define H_     256
#define STEPS_ 24
#define BS_    (B_ * S_)      // 65536
#define NPACK  1280           // 5 gates * 256
#define KSL    16             // 512/32 k-slabs
#define KSLP   10             // 320/32 (proj K padded)

typedef __bf16 bf16x8 __attribute__((ext_vector_type(8)));
typedef float  f32x4  __attribute__((ext_vector_type(4)));

__device__ __forceinline__ float sigm(float x) {
    return 1.0f / (1.0f + __expf(-x));
}
__device__ __forceinline__ float fast_tanh(float x) {
    return 2.0f * sigm(2.0f * x) - 1.0f;
}

// ---------------------------------------------------------------------------
// Pack step-GEMM B: Bp[ks][p][kin], p = w*80 + g*16 + c_lo, col c = w*16+c_lo.
// k<256 -> U_*_l[k], k>=256 -> U_*_r[k-256]. Gates: 0=i,1=o,2=u,3=f_l,4=f_r.
// ---------------------------------------------------------------------------
__global__ __launch_bounds__(256) void pack_B_kernel(
    const float* __restrict__ U_iou_l, const float* __restrict__ U_iou_r,
    const float* __restrict__ U_f_ll,  const float* __restrict__ U_f_lr,
    const float* __restrict__ U_f_rl,  const float* __restrict__ U_f_rr,
    __hip_bfloat16* __restrict__ Bp)
{
    const int idx = blockIdx.x * 256 + threadIdx.x;      // 16*1280*32 = 655360
    if (idx >= KSL * NPACK * 32) return;
    const int ks = idx / (NPACK * 32);
    const int rem = idx - ks * (NPACK * 32);
    const int p = rem >> 5;
    const int kin = rem & 31;
    const int k = ks * 32 + kin;
    const int w = p / 80;
    const int rg = p - w * 80;
    const int g = rg >> 4;
    const int c = w * 16 + (rg & 15);
    float v;
    if (g < 3) {
        const int col = g * 256 + c;
        v = (k < 256) ? U_iou_l[k * 768 + col] : U_iou_r[(k - 256) * 768 + col];
    } else if (g == 3) {
        v = (k < 256) ? U_f_ll[k * 256 + c] : U_f_lr[(k - 256) * 256 + c];
    } else {
        v = (k < 256) ? U_f_rl[k * 256 + c] : U_f_rr[(k - 256) * 256 + c];
    }
    Bp[idx] = __float2bfloat16(v);
}

// ---------------------------------------------------------------------------
// Pack projection weights for gate-interleaved output:
// Wp[ks][p][kin]; p = cw*64 + g*16 + c_lo; col = cw*16+c_lo;
// g in {0=i,1=o,2=u,3=f}. k>=300 zero-padded.
// ---------------------------------------------------------------------------
__global__ __launch_bounds__(256) void pack_W_kernel(
    const float* __restrict__ W_iou, const float* __restrict__ W_f,
    __hip_bfloat16* __restrict__ Wp)
{
    const int idx = blockIdx.x * 256 + threadIdx.x;      // 10*1024*32 = 327680
    if (idx >= KSLP * 1024 * 32) return;
    const int ks = idx / (1024 * 32);
    const int rem = idx - ks * (1024 * 32);
    const int p = rem >> 5;
    const int kin = rem & 31;
    const int k = ks * 32 + kin;
    const int cw = p >> 6;
    const int g = (p >> 4) & 3;
    const int col = cw * 16 + (p & 15);
    float v = 0.f;
    if (k < E_) v = (g < 3) ? W_iou[k * 768 + g * 256 + col] : W_f[k * 256 + col];
    Wp[idx] = __float2bfloat16(v);
}

// ---------------------------------------------------------------------------
// Winner: winner[t][b][d] = max s with tree_ids[b][t][s]==d (last-wins scatter)
// ---------------------------------------------------------------------------
__global__ __launch_bounds__(256) void winner_kernel(
    const int* __restrict__ tree_ids, int* __restrict__ winner)
{
    const int idx = blockIdx.x * 256 + threadIdx.x;
    if (idx >= B_ * STEPS_ * S_) return;
    const int b = idx / (STEPS_ * S_);
    const int rem = idx - b * (STEPS_ * S_);
    const int t = rem / S_;
    const int s = rem - t * S_;
    const int d = tree_ids[idx];
    if ((unsigned)d < (unsigned)S_)
        atomicMax(&winner[(size_t)t * BS_ + b * S_ + d], s);
}

// ---------------------------------------------------------------------------
// Projection GEMM (MFMA): writes gate-interleaved x_pack[row][256 cols][4 g]
// (bf16, 1024 elems/row). Block: 256 thr, M=16, K=320. Wave owns h-cols
// [wave*64, wave*64+64) x 4 gates = 16 N-tiles (nt = chunk*4 + g).
// ---------------------------------------------------------------------------
__global__ __launch_bounds__(256) void proj_kernel(
    const float* __restrict__ input, const __hip_bfloat16* __restrict__ Wp,
    const float* __restrict__ b_iou, const float* __restrict__ b_f,
    __hip_bfloat16* __restrict__ x_pack)
{
    __shared__ __hip_bfloat16 Ash[16][328];              // +8 pad
    const int tid = threadIdx.x;
    const int row0 = blockIdx.x * 16;

    // Stage A: fp32 -> bf16, 16 rows x 320 (zeros past 300)
    for (int it = 0; it < 5; ++it) {
        const int idx = tid + it * 256;                  // 16 rows * 80 chunks
        const int r = idx / 80;
        const int c4 = idx - r * 80;
        float4 v = make_float4(0.f, 0.f, 0.f, 0.f);
        if (c4 < 75) v = *(const float4*)(input + (size_t)(row0 + r) * E_ + c4 * 4);
        union { __hip_bfloat16 h[4]; uint2 u; } tconv;
        tconv.h[0] = __float2bfloat16(v.x);
        tconv.h[1] = __float2bfloat16(v.y);
        tconv.h[2] = __float2bfloat16(v.z);
        tconv.h[3] = __float2bfloat16(v.w);
        *(uint2*)&Ash[r][c4 * 4] = tconv.u;
    }
    __syncthreads();

    const int lane = tid & 63;
    const int wave = tid >> 6;
    const int m16 = lane & 15;
    const int q = lane >> 4;

    f32x4 acc[16];
    const f32x4 z4 = {0.f, 0.f, 0.f, 0.f};
#pragma unroll
    for (int nt = 0; nt < 16; ++nt) acc[nt] = z4;

    const __hip_bfloat16* wp = Wp + ((size_t)(wave * 256 + m16)) * 32 + q * 8;
    for (int ks = 0; ks < KSLP; ++ks) {
        const bf16x8 a = *reinterpret_cast<const bf16x8*>(&Ash[m16][ks * 32 + q * 8]);
        const __hip_bfloat16* wk = wp + (size_t)ks * 32768;
#pragma unroll
        for (int nt = 0; nt < 16; ++nt) {
            const bf16x8 bb = *reinterpret_cast<const bf16x8*>(wk + nt * 512);
            acc[nt] = __builtin_amdgcn_mfma_f32_16x16x32_bf16(a, bb, acc[nt], 0, 0, 0);
        }
    }

    // Epilogue: 4 gates per (row, col) live in this thread -> one uint2 store
#pragma unroll
    for (int j = 0; j < 4; ++j) {
        const int row = row0 + q * 4 + j;
        const size_t xrow = (size_t)row * 1024;
#pragma unroll
        for (int chunk = 0; chunk < 4; ++chunk) {
            const int c = (wave * 4 + chunk) * 16 + m16;   // h-col
            union { __hip_bfloat16 h[4]; uint2 u; } pk;
            pk.h[0] = __float2bfloat16(acc[chunk * 4 + 0][j] + b_iou[c]);
            pk.h[1] = __float2bfloat16(acc[chunk * 4 + 1][j] + b_iou[256 + c]);
            pk.h[2] = __float2bfloat16(acc[chunk * 4 + 2][j] + b_iou[512 + c]);
            pk.h[3] = __float2bfloat16(acc[chunk * 4 + 3][j] + b_f[c]);
            *(uint2*)(x_pack + xrow + (size_t)c * 4) = pk.u;
        }
    }
}

// ---------------------------------------------------------------------------
// Copy-through + null-slot zero. h and c both bf16: one uint4 chunk of each.
// idx over BS*32 chunks (16B per chunk per array).
// ---------------------------------------------------------------------------
__global__ __launch_bounds__(256) void copy_kernel(
    const uint4* __restrict__ h_cur4, uint4* __restrict__ h_next4,
    const uint4* __restrict__ c_cur4, uint4* __restrict__ c_next4,
    const int* __restrict__ winner_t)
{
    const int idx = blockIdx.x * 256 + threadIdx.x;      // BS*32
    const int row = idx >> 5;
    const int d = row & (S_ - 1);
    if (d == 0) {
        const uint4 z = make_uint4(0u, 0u, 0u, 0u);
        h_next4[idx] = z;
        c_next4[idx] = z;
    } else if (winner_t[row] < 0) {
        h_next4[idx] = h_cur4[idx];
        c_next4[idx] = c_cur4[idx];
    }
}

// ---------------------------------------------------------------------------
// Fused MFMA step. Block: 256 thr (4 waves), M=32 rows.
// Staging: h_l|h_r (32x512 bf16) AND c_l,c_r (32x256 bf16 each) -> LDS in one
// batched coalesced phase. K-loop: B frags from global (L2-resident).
// Epilogue: x via one 8B gate-interleaved load; c from LDS; bf16 writes.
// ---------------------------------------------------------------------------
__global__ __launch_bounds__(256, 2) void step_kernel(
    const __hip_bfloat16* __restrict__ h_cur, const __hip_bfloat16* __restrict__ c_cur,
    __hip_bfloat16* __restrict__ h_next, __hip_bfloat16* __restrict__ c_next,
    const int* __restrict__ tree_ids, const int* __restrict__ tree_ids_l,
    const int* __restrict__ tree_ids_r, const int* __restrict__ winner_t,
    const __hip_bfloat16* __restrict__ x_pack,
    const __hip_bfloat16* __restrict__ Bp, int t)
{
    const int b = blockIdx.x >> 6;            // 64 tiles of 32 rows per batch
    const int tile = blockIdx.x & 63;
    const int s0 = tile * 32;
    const int tid = threadIdx.x;

    __shared__ __hip_bfloat16 Ash[32][520];    // 32 x (512 + 8 pad) = 33.3 KB
    __shared__ __hip_bfloat16 Csh[2][32][264]; // c_l/c_r tiles, +8 pad = 33.8 KB
    __shared__ int sIdl[32], sIdr[32], sIdd[32];

    const int* idd_b = tree_ids   + ((size_t)b * STEPS_ + t) * S_;
    const int* idl_b = tree_ids_l + ((size_t)b * STEPS_ + t) * S_;
    const int* idr_b = tree_ids_r + ((size_t)b * STEPS_ + t) * S_;

    if (tid < 32)       sIdl[tid]      = idl_b[s0 + tid];
    else if (tid < 64)  sIdr[tid - 32] = idr_b[s0 + tid - 32];
    else if (tid < 96)  sIdd[tid - 64] = idd_b[s0 + tid - 64];
    __syncthreads();

    // Batched staging: h (2048 chunks) + c_l/c_r (2048 chunks), 16B each
#pragma unroll
    for (int it = 0; it < 16; ++it) {
        const int idx = tid + it * 256;        // 0..4095
        if (idx < 2048) {
            const int r = idx >> 6;            // 64 chunks per h row
            const int ch = idx & 63;
            const int half = ch >> 5;
            const int c16 = ch & 31;
            const int src = half ? sIdr[r] : sIdl[r];
            const uint4 v = *(const uint4*)(h_cur + ((size_t)(b * S_) + src) * H_ + c16 * 8);
            *(uint4*)&Ash[r][half * 256 + c16 * 8] = v;
        } else {
            const int idx2 = idx - 2048;
            const int r = idx2 >> 6;           // 64 chunks: 2 halves x 32
            const int ch = idx2 & 63;
            const int half = ch >> 5;
            const int c16 = ch & 31;
            const int src = half ? sIdr[r] : sIdl[r];
            const uint4 v = *(const uint4*)(c_cur + ((size_t)(b * S_) + src) * H_ + c16 * 8);
            *(uint4*)&Csh[half][r][c16 * 8] = v;
        }
    }
    __syncthreads();

    const int lane = tid & 63;
    const int wave = tid >> 6;
    const int m16 = lane & 15;
    const int q = lane >> 4;

    f32x4 acc[2][4][5];
    const f32x4 z4 = {0.f, 0.f, 0.f, 0.f};
#pragma unroll
    for (int sm = 0; sm < 2; ++sm)
#pragma unroll
        for (int wg = 0; wg < 4; ++wg)
#pragma unroll
            for (int g = 0; g < 5; ++g) acc[sm][wg][g] = z4;

    const __hip_bfloat16* bp_base = Bp + ((size_t)(wave * 320 + m16)) * 32 + q * 8;

    for (int ks = 0; ks < KSL; ++ks) {
        const bf16x8 a0 = *reinterpret_cast<const bf16x8*>(&Ash[m16][ks * 32 + q * 8]);
        const bf16x8 a1 = *reinterpret_cast<const bf16x8*>(&Ash[16 + m16][ks * 32 + q * 8]);
        const __hip_bfloat16* bk = bp_base + (size_t)ks * (NPACK * 32);
#pragma unroll
        for (int wg = 0; wg < 4; ++wg) {
            bf16x8 bfrag[5];
#pragma unroll
            for (int g = 0; g < 5; ++g)
                bfrag[g] = *reinterpret_cast<const bf16x8*>(bk + (wg * 80 + g * 16) * 32);
#pragma unroll
            for (int g = 0; g < 5; ++g) {
                acc[0][wg][g] = __builtin_amdgcn_mfma_f32_16x16x32_bf16(a0, bfrag[g], acc[0][wg][g], 0, 0, 0);
                acc[1][wg][g] = __builtin_amdgcn_mfma_f32_16x16x32_bf16(a1, bfrag[g], acc[1][wg][g], 0, 0, 0);
            }
        }
    }

    // Epilogue: C layout col=lane&15, row=q*4+j (per 16x16 sub-tile)
#pragma unroll
    for (int sm = 0; sm < 2; ++sm) {
#pragma unroll
        for (int j = 0; j < 4; ++j) {
            const int r = sm * 16 + q * 4 + j;    // local row
            const int s = s0 + r;
            const int d = sIdd[r];
            if (d == 0) continue;
            if (winner_t[b * S_ + d] != s) continue;
            const size_t xbase = ((size_t)(b * S_ + s)) * 1024;
            const size_t orow = ((size_t)(b * S_ + d)) * H_;
#pragma unroll
            for (int wg = 0; wg < 4; ++wg) {
                const int c = (wave * 4 + wg) * 16 + m16;
                union { uint2 u; __hip_bfloat16 x[4]; } xv;
                xv.u = *(const uint2*)(x_pack + xbase + (size_t)c * 4);
                const float xi = __bfloat162float(xv.x[0]);
                const float xo = __bfloat162float(xv.x[1]);
                const float xu = __bfloat162float(xv.x[2]);
                const float xf = __bfloat162float(xv.x[3]);
                const float ig = sigm(acc[sm][wg][0][j] + xi);
                const float og = sigm(acc[sm][wg][1][j] + xo);
                const float ug = fast_tanh(acc[sm][wg][2][j] + xu);
                const float fl = sigm(acc[sm][wg][3][j] + xf);
                const float fr = sigm(acc[sm][wg][4][j] + xf);
                const float cl = __bfloat162float(Csh[0][r][c]);
                const float cr = __bfloat162float(Csh[1][r][c]);
                const float cn = ig * ug + fl * cl + fr * cr;
                const float hn = og * fast_tanh(cn);
                c_next[orow + c] = __float2bfloat16(cn);
                h_next[orow + c] = __float2bfloat16(hn);
            }
        }
    }
}

// ---------------------------------------------------------------------------
// Final h,c bf16 -> fp32 into d_out
// ---------------------------------------------------------------------------
__global__ __launch_bounds__(256) void convert_kernel(
    const __hip_bfloat16* __restrict__ h, const __hip_bfloat16* __restrict__ c,
    float* __restrict__ out_h, float* __restrict__ out_c)
{
    const size_t i = ((size_t)blockIdx.x * 256 + threadIdx.x) * 8;
#pragma unroll
    for (int j = 0; j < 8; ++j) {
        out_h[i + j] = __bfloat162float(h[i + j]);
        out_c[i + j] = __bfloat162float(c[i + j]);
    }
}

// ---------------------------------------------------------------------------
// Root: roots[b] = max_s tree_ids[b, STEPS-1, s]; h_root = h[b, root]
// ---------------------------------------------------------------------------
__global__ __launch_bounds__(256) void root_kernel(
    const int* __restrict__ tree_ids,
    const __hip_bfloat16* __restrict__ h, float* __restrict__ h_root)
{
    const int b = blockIdx.x;
    const int tid = threadIdx.x;
    const int* ids = tree_ids + ((size_t)b * STEPS_ + (STEPS_ - 1)) * S_;
    __shared__ int red[256];
    int m = 0;
    for (int s = tid; s < S_; s += 256) m = max(m, ids[s]);
    red[tid] = m;
    __syncthreads();
    for (int off = 128; off > 0; off >>= 1) {
        if (tid < off) red[tid] = max(red[tid], red[tid + off]);
        __syncthreads();
    }
    const int root = red[0];
    h_root[(size_t)b * H_ + tid] =
        __bfloat162float(h[((size_t)(b * S_) + root) * H_ + tid]);
}

// ---------------------------------------------------------------------------
extern "C" void kernel_launch(void* const* d_in, const int* in_sizes, int n_in,
                              void* d_out, int out_size, void* d_ws, size_t ws_size,
                              hipStream_t stream)
{
    const float* input_ids  = (const float*)d_in[0];
    const int*   tree_ids   = (const int*)d_in[1];
    const int*   tree_ids_r = (const int*)d_in[2];
    const int*   tree_ids_l = (const int*)d_in[3];
    const float* W_iou   = (const float*)d_in[4];
    const float* b_iou   = (const float*)d_in[5];
    const float* U_iou_l = (const float*)d_in[6];
    const float* U_iou_r = (const float*)d_in[7];
    const float* W_f     = (const float*)d_in[8];
    const float* b_f     = (const float*)d_in[9];
    const float* U_f_ll  = (const float*)d_in[10];
    const float* U_f_lr  = (const float*)d_in[11];
    const float* U_f_rl  = (const float*)d_in[12];
    const float* U_f_rr  = (const float*)d_in[13];

    float* out = (float*)d_out;
    float* out_h = out;
    float* out_c = out + (size_t)BS_ * H_;
    float* out_root = out + (size_t)2 * BS_ * H_;

    // ws layout (bytes):
    //   x_pack bf16 [BS][1024]   : 0          .. 134217728
    //   hA     bf16 [BS][256]    : 134217728  .. 167772160
    //   cA     bf16 [BS][256]    : 167772160  .. 201326592
    //   winner int  [24][B][S]   : 201326592  .. 207618048
    //   Bp     bf16 [16][1280][32]: 207618048 .. 208928768
    //   Wp     bf16 [10][1024][32]: 208928768 .. 209584128
    char* ws = (char*)d_ws;
    __hip_bfloat16* x_pack = (__hip_bfloat16*)(ws);
    __hip_bfloat16* hA     = (__hip_bfloat16*)(ws + 134217728ull);
    __hip_bfloat16* cA     = (__hip_bfloat16*)(ws + 167772160ull);
    int*            winner = (int*)(ws + 201326592ull);
    __hip_bfloat16* Bp     = (__hip_bfloat16*)(ws + 207618048ull);
    __hip_bfloat16* Wp     = (__hip_bfloat16*)(ws + 208928768ull);
    // Ping-pong partners live in d_out's h/c regions (fp32-sized, so roomy)
    __hip_bfloat16* hB     = (__hip_bfloat16*)out_h;
    __hip_bfloat16* cB     = (__hip_bfloat16*)out_c;

    hipMemsetAsync(hA, 0, (size_t)BS_ * H_ * sizeof(__hip_bfloat16), stream);
    hipMemsetAsync(cA, 0, (size_t)BS_ * H_ * sizeof(__hip_bfloat16), stream);
    hipMemsetAsync(winner, 0xFF, (size_t)STEPS_ * BS_ * sizeof(int), stream);

    pack_B_kernel<<<(KSL * NPACK * 32 + 255) / 256, 256, 0, stream>>>(
        U_iou_l, U_iou_r, U_f_ll, U_f_lr, U_f_rl, U_f_rr, Bp);
    pack_W_kernel<<<(KSLP * 1024 * 32 + 255) / 256, 256, 0, stream>>>(W_iou, W_f, Wp);
    winner_kernel<<<(B_ * STEPS_ * S_) / 256, 256, 0, stream>>>(tree_ids, winner);
    proj_kernel<<<BS_ / 16, 256, 0, stream>>>(input_ids, Wp, b_iou, b_f, x_pack);

    for (int t = 0; t < STEPS_; ++t) {
        const __hip_bfloat16* hc = (t & 1) ? hB : hA;
        const __hip_bfloat16* cc = (t & 1) ? cB : cA;
        __hip_bfloat16*       hn = (t & 1) ? hA : hB;
        __hip_bfloat16*       cn = (t & 1) ? cA : cB;
        const int* wt = winner + (size_t)t * BS_;

        copy_kernel<<<(BS_ * 32) / 256, 256, 0, stream>>>(
            (const uint4*)hc, (uint4*)hn, (const uint4*)cc, (uint4*)cn, wt);

        step_kernel<<<B_ * (S_ / 32), 256, 0, stream>>>(
            hc, cc, hn, cn, tree_ids, tree_ids_l, tree_ids_r, wt,
            x_pack, Bp, t);
    }

    // t=23 (odd) wrote hA/cA: convert to fp32 into d_out
    convert_kernel<<<(BS_ * H_ / 8) / 256, 256, 0, stream>>>(hA, cA, out_h, out_c);
    root_kernel<<<B_, 256, 0, stream>>>(tree_ids, hA, out_root);
}